// Round 2
// baseline (537.643 us; speedup 1.0000x reference)
//
#include <hip/hip_runtime.h>

// Problem constants
// B=4, HT=WT=256, WS=8, NH=8, VD=128, HD=16, WH=WW=32
// windows: 4*32*32 = 4096, tokens/window = 64, head dim (values)=16, concat qk dim = 32

typedef __bf16 bf16_t;
typedef __bf16 bf16x4 __attribute__((ext_vector_type(4)));
typedef __bf16 bf16x8 __attribute__((ext_vector_type(8)));
typedef float f32x4 __attribute__((ext_vector_type(4)));

#define SMEM_BYTES 155648
// LDS layout (bytes):
//   0      XV [64][136] bf16 (17408)     -- overlaid in phase 2 by P: 8 waves x [32][72] bf16 (36864)
//   17408  XC [64][136] bf16 (17408)
//   36864  Q  [8][64][40] bf16 (40960)   row stride 40 elems (80B, 16B aligned, 2-way banks)
//   77824  K  [8][64][40] bf16 (40960)
//   118784 Vt [8][16][72] bf16 (18432)   V transposed: [head][e][token], stride 72 (144B)
//   137216 Y  [64][136] bf16 (17408)
//   154624 POS[225] f32 (912)
// total 155536

// ---------------- weight pre-swizzle into B-fragment order ----------------
// Fragment f holds 512 bf16: elem (lane l, j) = W[k = ks*32 + (l>>4)*8 + j][n0 + (l&15)]
// frags 0..95   : Wv (ld 384), nt in [0,24), f = nt*4+ks
// frags 96..159 : Wc (ld 256), nt in [0,16), f = 96 + nt*4+ks
// frags 160..191: Wo (ld 128), nt in [0,8),  f = 160 + nt*4+ks
__global__ __launch_bounds__(512) void prep_weights_k(
    const float* __restrict__ Wv, const float* __restrict__ Wc,
    const float* __restrict__ Wo, bf16_t* __restrict__ wsW) {
  int g = blockIdx.x * 512 + threadIdx.x;   // 192*512 = 98304 total
  int frag = g >> 9;
  int within = g & 511;
  int l = within >> 3, j = within & 7;
  int col16 = l & 15, kg = l >> 4;
  float val;
  if (frag < 96) {
    int nt = frag >> 2, ks = frag & 3;
    int k = ks * 32 + kg * 8 + j;
    val = Wv[k * 384 + nt * 16 + col16];
  } else if (frag < 160) {
    int f = frag - 96;
    int nt = f >> 2, ks = f & 3;
    int k = ks * 32 + kg * 8 + j;
    val = Wc[k * 256 + nt * 16 + col16];
  } else {
    int f = frag - 160;
    int nt = f >> 2, ks = f & 3;
    int k = ks * 32 + kg * 8 + j;
    val = Wo[k * 128 + nt * 16 + col16];
  }
  wsW[g] = (bf16_t)val;
}

// ---------------- fused windowed attention ----------------
// 512 threads = 8 waves (2 waves/SIMD). One window per block.
__global__ __launch_bounds__(512, 1) void swin_fused_k(
    const float* __restrict__ gxv, const float* __restrict__ gxc,
    const float* __restrict__ bv, const float* __restrict__ bc,
    const float* __restrict__ pos_g, const float* __restrict__ bo,
    const bf16_t* __restrict__ wsW, float* __restrict__ out) {
  extern __shared__ char smem[];
  bf16_t* XV = (bf16_t*)(smem);
  bf16_t* XC = (bf16_t*)(smem + 17408);
  bf16_t* P  = (bf16_t*)(smem);            // overlays XV/XC after GEMM phase
  bf16_t* Q  = (bf16_t*)(smem + 36864);
  bf16_t* K  = (bf16_t*)(smem + 77824);
  bf16_t* Vt = (bf16_t*)(smem + 118784);
  bf16_t* Y  = (bf16_t*)(smem + 137216);
  float*  POS = (float*)(smem + 154624);

  const int tid = threadIdx.x;
  const int l = tid & 63;
  const int w = tid >> 6;          // wave id, 0..7
  const int col16 = l & 15;
  const int kg = l >> 4;

  const int bid = blockIdx.x;
  const int b = bid >> 10;
  const int rem = bid & 1023;
  const int wy = rem >> 5, wx = rem & 31;
  const bool lastRow = (wy == 31), lastCol = (wx == 31);

  if (tid < 225) POS[tid] = pos_g[tid];

  // ---- stage rolled inputs to LDS as bf16 ----
  {
    const int t = tid >> 3, q = tid & 7;               // token, eighth
    const int rs = ((wy << 3) + (t >> 3) + 4) & 255;   // roll -4 => src = dst+4 mod 256
    const int cs = ((wx << 3) + (t & 7) + 4) & 255;
    const size_t base = ((size_t)b * 65536 + (size_t)rs * 256 + (size_t)cs) * 128;
    const float4* pv = (const float4*)(gxv + base) + q * 4;
    const float4* pc = (const float4*)(gxc + base) + q * 4;
    bf16_t* dv = XV + t * 136 + q * 16;
    bf16_t* dc = XC + t * 136 + q * 16;
#pragma unroll
    for (int i = 0; i < 4; ++i) {
      float4 a = pv[i];
      dv[i * 4 + 0] = (bf16_t)a.x; dv[i * 4 + 1] = (bf16_t)a.y;
      dv[i * 4 + 2] = (bf16_t)a.z; dv[i * 4 + 3] = (bf16_t)a.w;
      float4 c = pc[i];
      dc[i * 4 + 0] = (bf16_t)c.x; dc[i * 4 + 1] = (bf16_t)c.y;
      dc[i * 4 + 2] = (bf16_t)c.z; dc[i * 4 + 3] = (bf16_t)c.w;
    }
  }
  __syncthreads();

  // ---- Phase 1: QKV/coords GEMM, scatter into Q/K/Vt (per-head layout) ----
  // wave w owns v-tiles [3w,3w+3) of 24 and c-tiles [2w,2w+2) of 16.
  {
    bf16x8 aA[4][4];
    // ---- v part ----
#pragma unroll
    for (int mi = 0; mi < 4; ++mi)
#pragma unroll
      for (int ks = 0; ks < 4; ++ks)
        aA[mi][ks] = *(const bf16x8*)(XV + (mi * 16 + col16) * 136 + ks * 32 + kg * 8);
    bf16x8 bWv[12];
#pragma unroll
    for (int jt = 0; jt < 3; ++jt)
#pragma unroll
      for (int ks = 0; ks < 4; ++ks)
        bWv[jt * 4 + ks] =
            *(const bf16x8*)(wsW + ((((w * 3 + jt) << 2) + ks) << 9) + (l << 3));
#pragma unroll
    for (int jt = 0; jt < 3; ++jt) {
      const int nt = w * 3 + jt;
      f32x4 acc[4] = {};
#pragma unroll
      for (int ks = 0; ks < 4; ++ks)
#pragma unroll
        for (int mi = 0; mi < 4; ++mi)
          acc[mi] = __builtin_amdgcn_mfma_f32_16x16x32_bf16(
              aA[mi][ks], bWv[jt * 4 + ks], acc[mi], 0, 0, 0);
      // epilogue scatter: global col G -> (d = G/3, kk = G%3), d = e*8+h
      const int G = nt * 16 + col16;
      const unsigned du = (unsigned)G / 3u;
      const int kk = G - 3 * (int)du;
      const int e = (int)du >> 3, h = (int)du & 7;
      const float bias = bv[G];
      if (kk == 2) {
        bf16_t* dst = Vt + h * 1152 + e * 72 + kg * 4;  // Vt[h][e][token]
#pragma unroll
        for (int mi = 0; mi < 4; ++mi) {
          bf16x4 pk;
#pragma unroll
          for (int r = 0; r < 4; ++r) pk[r] = (bf16_t)(acc[mi][r] + bias);
          *(bf16x4*)(dst + mi * 16) = pk;               // 8B write, 8B aligned
        }
      } else {
        bf16_t* dst = (kk == 0 ? Q : K) + h * 2560 + e;  // [h][token][e], stride 40
#pragma unroll
        for (int mi = 0; mi < 4; ++mi)
#pragma unroll
          for (int r = 0; r < 4; ++r)
            dst[(mi * 16 + kg * 4 + r) * 40] = (bf16_t)(acc[mi][r] + bias);
      }
    }
    // ---- c part ----
#pragma unroll
    for (int mi = 0; mi < 4; ++mi)
#pragma unroll
      for (int ks = 0; ks < 4; ++ks)
        aA[mi][ks] = *(const bf16x8*)(XC + (mi * 16 + col16) * 136 + ks * 32 + kg * 8);
    bf16x8 bWc[8];
#pragma unroll
    for (int jt = 0; jt < 2; ++jt)
#pragma unroll
      for (int ks = 0; ks < 4; ++ks)
        bWc[jt * 4 + ks] =
            *(const bf16x8*)(wsW + ((96 + ((w * 2 + jt) << 2) + ks) << 9) + (l << 3));
#pragma unroll
    for (int jt = 0; jt < 2; ++jt) {
      const int nt = w * 2 + jt;
      f32x4 acc[4] = {};
#pragma unroll
      for (int ks = 0; ks < 4; ++ks)
#pragma unroll
        for (int mi = 0; mi < 4; ++mi)
          acc[mi] = __builtin_amdgcn_mfma_f32_16x16x32_bf16(
              aA[mi][ks], bWc[jt * 4 + ks], acc[mi], 0, 0, 0);
      const int G = nt * 16 + col16;       // in [0,256)
      const int d = G >> 1, kk = G & 1;    // k innermost (qc,kc)
      const int e = d >> 3, h = d & 7;
      const float bias = bc[G];
      bf16_t* dst = (kk == 0 ? Q : K) + h * 2560 + 16 + e;  // coord half: cols 16..31
#pragma unroll
      for (int mi = 0; mi < 4; ++mi)
#pragma unroll
        for (int r = 0; r < 4; ++r)
          dst[(mi * 16 + kg * 4 + r) * 40] = (bf16_t)(acc[mi][r] + bias);
    }
  }
  __syncthreads();

  // ---- Phase 2: attention. wave w does head h=w. P (wave-private) overlays XV/XC. ----
  {
    const int h = w;
    bf16_t* Pw = P + w * 2304;   // [32][72] per wave (two query-halves reuse it)
    const bf16_t* Qh = Q + h * 2560;
    const bf16_t* Kh = K + h * 2560;
    bf16x8 aQ[4], bK[4];
#pragma unroll
    for (int mi = 0; mi < 4; ++mi)
      aQ[mi] = *(const bf16x8*)(Qh + (mi * 16 + col16) * 40 + kg * 8);
#pragma unroll
    for (int nj = 0; nj < 4; ++nj)
      bK[nj] = *(const bf16x8*)(Kh + (nj * 16 + col16) * 40 + kg * 8);
    f32x4 dacc[4][4];
#pragma unroll
    for (int mi = 0; mi < 4; ++mi)
#pragma unroll
      for (int nj = 0; nj < 4; ++nj) {
        f32x4 z = {};
        dacc[mi][nj] =
            __builtin_amdgcn_mfma_f32_16x16x32_bf16(aQ[mi], bK[nj], z, 0, 0, 0);
      }
    // two query-halves: hi=0 -> rows 0..31 (mi 0,1), hi=1 -> rows 32..63 (mi 2,3)
#pragma unroll
    for (int hi = 0; hi < 2; ++hi) {
      // softmax: row i = mi*16 + kg*4 + r; col j = nj*16 + col16
#pragma unroll
      for (int mi2 = 0; mi2 < 2; ++mi2) {
        const int mi = hi * 2 + mi2;
#pragma unroll
        for (int r = 0; r < 4; ++r) {
          const int i = mi * 16 + kg * 4 + r;
          const int ix = i >> 3, iy = i & 7;
          float tv[4];
#pragma unroll
          for (int nj = 0; nj < 4; ++nj) {
            const int j = nj * 16 + col16;
            float vvv = dacc[mi][nj][r] * 0.25f +
                        POS[((j >> 3) - ix + 7) * 15 + ((j & 7) - iy + 7)];
            if (lastRow && ((i ^ j) & 32)) vvv = -1e30f;  // w1 halves differ
            if (lastCol && ((i ^ j) & 4))  vvv = -1e30f;  // w2 halves differ
            tv[nj] = vvv;
          }
          float m = fmaxf(fmaxf(tv[0], tv[1]), fmaxf(tv[2], tv[3]));
#pragma unroll
          for (int s = 1; s < 16; s <<= 1) m = fmaxf(m, __shfl_xor(m, s, 64));
          float sum = 0.f;
#pragma unroll
          for (int nj = 0; nj < 4; ++nj) {
            tv[nj] = __expf(tv[nj] - m);
            sum += tv[nj];
          }
#pragma unroll
          for (int s = 1; s < 16; s <<= 1) sum += __shfl_xor(sum, s, 64);
          const float inv = __builtin_amdgcn_rcpf(sum);
#pragma unroll
          for (int nj = 0; nj < 4; ++nj)
            Pw[(mi2 * 16 + kg * 4 + r) * 72 + nj * 16 + col16] =
                (bf16_t)(tv[nj] * inv);
        }
      }
      // PV for this half: A = P[32x64], B = V[64x16] (from Vt, contiguous reads)
      f32x4 oacc[2] = {};
#pragma unroll
      for (int ks = 0; ks < 2; ++ks) {
        bf16x8 bV = *(const bf16x8*)(Vt + h * 1152 + col16 * 72 + ks * 32 + kg * 8);
#pragma unroll
        for (int mi2 = 0; mi2 < 2; ++mi2) {
          bf16x8 aP = *(const bf16x8*)(Pw + (mi2 * 16 + col16) * 72 + ks * 32 + kg * 8);
          oacc[mi2] =
              __builtin_amdgcn_mfma_f32_16x16x32_bf16(aP, bV, oacc[mi2], 0, 0, 0);
        }
      }
#pragma unroll
      for (int mi2 = 0; mi2 < 2; ++mi2)
#pragma unroll
        for (int r = 0; r < 4; ++r)
          Y[((hi * 2 + mi2) * 16 + kg * 4 + r) * 136 + h * 16 + col16] =
              (bf16_t)(oacc[mi2][r]);
    }
  }
  __syncthreads();

  // ---- Phase 3: output projection y[64][128] @ Wo + bo -> global ----
  // wave w owns output n-tile nto = w (cols 16w .. 16w+15)
  {
    bf16x8 aY[4][4];
#pragma unroll
    for (int mi = 0; mi < 4; ++mi)
#pragma unroll
      for (int ks = 0; ks < 4; ++ks)
        aY[mi][ks] = *(const bf16x8*)(Y + (mi * 16 + col16) * 136 + ks * 32 + kg * 8);
    bf16x8 bWo[4];
#pragma unroll
    for (int ks = 0; ks < 4; ++ks)
      bWo[ks] = *(const bf16x8*)(wsW + ((160 + (w << 2) + ks) << 9) + (l << 3));
    f32x4 acc[4] = {};
#pragma unroll
    for (int ks = 0; ks < 4; ++ks)
#pragma unroll
      for (int mi = 0; mi < 4; ++mi)
        acc[mi] = __builtin_amdgcn_mfma_f32_16x16x32_bf16(
            aY[mi][ks], bWo[ks], acc[mi], 0, 0, 0);
    const int o = w * 16 + col16;
    const float bias = bo[o];
    const int rg0 = wy << 3, cg0 = wx << 3;
#pragma unroll
    for (int mi = 0; mi < 4; ++mi)
#pragma unroll
      for (int r = 0; r < 4; ++r) {
        const int t = mi * 16 + kg * 4 + r;
        const int rg = rg0 + (t >> 3), cg = cg0 + (t & 7);
        out[(((size_t)b * 65536 + (size_t)rg * 256 + (size_t)cg) << 7) + o] =
            acc[mi][r] + bias;
      }
  }
}

extern "C" void kernel_launch(void* const* d_in, const int* in_sizes, int n_in,
                              void* d_out, int out_size, void* d_ws, size_t ws_size,
                              hipStream_t stream) {
  const float* gxv = (const float*)d_in[0];
  const float* gxc = (const float*)d_in[1];
  const float* Wv  = (const float*)d_in[2];
  const float* bv  = (const float*)d_in[3];
  const float* Wc  = (const float*)d_in[4];
  const float* bc  = (const float*)d_in[5];
  const float* pe  = (const float*)d_in[6];
  const float* Wo  = (const float*)d_in[7];
  const float* bo  = (const float*)d_in[8];
  float* out = (float*)d_out;
  bf16_t* wsW = (bf16_t*)d_ws;   // 192 KB of B-fragment-ordered bf16 weights

  hipFuncSetAttribute((const void*)swin_fused_k,
                      hipFuncAttributeMaxDynamicSharedMemorySize, SMEM_BYTES);
  prep_weights_k<<<192, 512, 0, stream>>>(Wv, Wc, Wo, wsW);
  swin_fused_k<<<4096, 512, SMEM_BYTES, stream>>>(gxv, gxc, bv, bc, pe, bo, wsW, out);
}

// Round 4
// 398.616 us; speedup vs baseline: 1.3488x; 1.3488x over previous
//
#include <hip/hip_runtime.h>

// B=4, HT=WT=256, WS=8, NH=8, VD=128, HD=16, WH=WW=32
// 4096 windows x 64 tokens; per head: qk-dim 32 (16 value + 16 coord), v-dim 16.
//
// Register-resident design: Q^T/K^T/V computed via transposed-weight MFMAs so
// their D-fragments feed the S^T and PV MFMAs directly (k-permutation trick);
// only X (input), Y (pre-projection) and POS go through LDS.

typedef __bf16 bf16_t;
typedef __bf16 bf16x4 __attribute__((ext_vector_type(4)));
typedef __bf16 bf16x8 __attribute__((ext_vector_type(8)));
typedef float f32x4 __attribute__((ext_vector_type(4)));

#define SMEM_BYTES 53248
// LDS: XV [64][136] bf16 @0 (17408) | XC @17408 | Y [64][136] @34816 | POS @52224

// ws layout (bf16 elems), 98304 elems = 196608 bytes total:
//   head h (h<8): base h*10240, frags of 512:
//     [0..3]  WqvT A-frags (ks 0..3)   elem(l,j) = Wv[ks*32+(l>>4)*8+j][((l&15)*8+h)*3+0]
//     [4..7]  WkvT                      ... +1
//     [8..11] WqcT  (from Wc)           Wc[kin][((l&15)*8+h)*2+0]
//     [12..15]WkcT                      ... +1
//     [16..19]WvV  B-frags              Wv[kin][((l&15)*8+h)*3+2]
//   Wo B-frags: 81920 + (nt*4+ks)*512:  Wo[kin][nt*16+(l&15)]
__global__ __launch_bounds__(512) void prep_weights_k(
    const float* __restrict__ Wv, const float* __restrict__ Wc,
    const float* __restrict__ Wo, bf16_t* __restrict__ wsW) {
  int g = blockIdx.x * 512 + threadIdx.x;   // 192*512 = 98304
  int frag = g >> 9, within = g & 511;
  int l = within >> 3, j = within & 7;
  int cc = l & 15;
  int kin_off = ((l >> 4) << 3) + j;
  float val;
  if (frag < 160) {
    int h = frag / 20, fi = frag % 20;
    int type = fi >> 2, ks = fi & 3;
    int kin = ks * 32 + kin_off;
    if (type == 0)      val = Wv[kin * 384 + (cc * 8 + h) * 3];
    else if (type == 1) val = Wv[kin * 384 + (cc * 8 + h) * 3 + 1];
    else if (type == 2) val = Wc[kin * 256 + (cc * 8 + h) * 2];
    else if (type == 3) val = Wc[kin * 256 + (cc * 8 + h) * 2 + 1];
    else                val = Wv[kin * 384 + (cc * 8 + h) * 3 + 2];
    wsW[g] = (bf16_t)val;
  } else {
    int f = frag - 160, nt = f >> 2, ks = f & 3;
    int kin = ks * 32 + kin_off;
    wsW[g] = (bf16_t)Wo[kin * 128 + nt * 16 + cc];
  }
}

__global__ __launch_bounds__(512) void swin_fused_k(
    const float* __restrict__ gxv, const float* __restrict__ gxc,
    const float* __restrict__ bv, const float* __restrict__ bc,
    const float* __restrict__ pos_g, const float* __restrict__ bo,
    const bf16_t* __restrict__ wsW, float* __restrict__ out) {
  extern __shared__ char smem[];
  bf16_t* XV = (bf16_t*)(smem);
  bf16_t* XC = (bf16_t*)(smem + 17408);
  bf16_t* Y  = (bf16_t*)(smem + 34816);
  float*  POS = (float*)(smem + 52224);

  const int tid = threadIdx.x;
  const int l = tid & 63;
  const int w = tid >> 6;          // wave id = head id
  const int col16 = l & 15;
  const int q = l >> 4;            // lane quad

  const int bid = blockIdx.x;
  const int b = bid >> 10;
  const int rem = bid & 1023;
  const int wy = rem >> 5, wx = rem & 31;
  const bool lastRow = (wy == 31), lastCol = (wx == 31);

  if (tid < 225) POS[tid] = pos_g[tid];

  const int h = w;
  // per-lane biases, straight from global (L2-hot, once per block)
  float bqv_[4], bkv_[4], bqc_[4], bkc_[4];
#pragma unroll
  for (int r = 0; r < 4; ++r) {
    const int ev = q * 4 + r;
    bqv_[r] = bv[(ev * 8 + h) * 3 + 0];
    bkv_[r] = bv[(ev * 8 + h) * 3 + 1];
    bqc_[r] = bc[(ev * 8 + h) * 2 + 0];
    bkc_[r] = bc[(ev * 8 + h) * 2 + 1];
  }
  const float bvv = bv[(col16 * 8 + h) * 3 + 2];

  // ---- stage rolled inputs -> LDS bf16 [64][136] ----
  {
    const int t = tid >> 3, qq = tid & 7;
    const int rs = ((wy << 3) + (t >> 3) + 4) & 255;
    const int cs = ((wx << 3) + (t & 7) + 4) & 255;
    const size_t base = ((size_t)b * 65536 + (size_t)rs * 256 + (size_t)cs) * 128;
    const float4* pv = (const float4*)(gxv + base);
    const float4* pc = (const float4*)(gxc + base);
#pragma unroll
    for (int i = 0; i < 4; ++i) {
      float4 a = pv[i * 8 + qq];
      bf16x4 pk; pk[0]=(bf16_t)a.x; pk[1]=(bf16_t)a.y; pk[2]=(bf16_t)a.z; pk[3]=(bf16_t)a.w;
      *(bf16x4*)(XV + t * 136 + (i * 8 + qq) * 4) = pk;
      float4 c = pc[i * 8 + qq];
      bf16x4 qk; qk[0]=(bf16_t)c.x; qk[1]=(bf16_t)c.y; qk[2]=(bf16_t)c.z; qk[3]=(bf16_t)c.w;
      *(bf16x4*)(XC + t * 136 + (i * 8 + qq) * 4) = qk;
    }
  }
  __syncthreads();

  const bf16_t* wsH = wsW + h * 10240;

  bf16x8 xf[4][4];
  // ---- XV-derived: qv, kv, V ----
#pragma unroll
  for (int ni = 0; ni < 4; ++ni)
#pragma unroll
    for (int ks = 0; ks < 4; ++ks)
      xf[ni][ks] = *(const bf16x8*)(XV + (ni * 16 + col16) * 136 + ks * 32 + q * 8);
  f32x4 qa[4] = {}, ka[4] = {}, va[4] = {};
#pragma unroll
  for (int ks = 0; ks < 4; ++ks) {
    bf16x8 wq = *(const bf16x8*)(wsH + (0  + ks) * 512 + l * 8);
    bf16x8 wk = *(const bf16x8*)(wsH + (4  + ks) * 512 + l * 8);
    bf16x8 wv = *(const bf16x8*)(wsH + (16 + ks) * 512 + l * 8);
#pragma unroll
    for (int t4 = 0; t4 < 4; ++t4) {
      qa[t4] = __builtin_amdgcn_mfma_f32_16x16x32_bf16(wq, xf[t4][ks], qa[t4], 0, 0, 0);
      ka[t4] = __builtin_amdgcn_mfma_f32_16x16x32_bf16(wk, xf[t4][ks], ka[t4], 0, 0, 0);
      va[t4] = __builtin_amdgcn_mfma_f32_16x16x32_bf16(xf[t4][ks], wv, va[t4], 0, 0, 0);
    }
  }
  // pack V A-frags (token sigma mapping): slot(q,jj) -> token 16*(2ks+(jj>=4)) + 4q + (jj&3)
  bf16x8 aV[2];
#pragma unroll
  for (int ks2 = 0; ks2 < 2; ++ks2)
#pragma unroll
    for (int jj = 0; jj < 8; ++jj)
      aV[ks2][jj] = (bf16_t)(va[2 * ks2 + (jj >> 2)][jj & 3] + bvv);

  // ---- XC-derived: qc, kc ----
#pragma unroll
  for (int ni = 0; ni < 4; ++ni)
#pragma unroll
    for (int ks = 0; ks < 4; ++ks)
      xf[ni][ks] = *(const bf16x8*)(XC + (ni * 16 + col16) * 136 + ks * 32 + q * 8);
  f32x4 qc[4] = {}, kc[4] = {};
#pragma unroll
  for (int ks = 0; ks < 4; ++ks) {
    bf16x8 wq = *(const bf16x8*)(wsH + (8  + ks) * 512 + l * 8);
    bf16x8 wk = *(const bf16x8*)(wsH + (12 + ks) * 512 + l * 8);
#pragma unroll
    for (int t4 = 0; t4 < 4; ++t4) {
      qc[t4] = __builtin_amdgcn_mfma_f32_16x16x32_bf16(wq, xf[t4][ks], qc[t4], 0, 0, 0);
      kc[t4] = __builtin_amdgcn_mfma_f32_16x16x32_bf16(wk, xf[t4][ks], kc[t4], 0, 0, 0);
    }
  }
  // pack S^T operands (channel pi mapping): slot(q,jj) -> ch (jj<4 ? 4q+jj : 16+4q+jj-4)
  bf16x8 aK[4], bQ[4];
#pragma unroll
  for (int m = 0; m < 4; ++m) {
#pragma unroll
    for (int r = 0; r < 4; ++r) {
      aK[m][r]     = (bf16_t)(ka[m][r] + bkv_[r]);
      aK[m][4 + r] = (bf16_t)(kc[m][r] + bkc_[r]);
      bQ[m][r]     = (bf16_t)(qa[m][r] + bqv_[r]);
      bQ[m][4 + r] = (bf16_t)(qc[m][r] + bqc_[r]);
    }
  }

  // ---- S^T = K~ . Q~^T : lane col = i-token, rows = j-token ----
  f32x4 s[4][4];
  const f32x4 zz = {0.f, 0.f, 0.f, 0.f};
#pragma unroll
  for (int mj = 0; mj < 4; ++mj)
#pragma unroll
    for (int ni = 0; ni < 4; ++ni)
      s[mj][ni] = __builtin_amdgcn_mfma_f32_16x16x32_bf16(aK[mj], bQ[ni], zz, 0, 0, 0);

  // ---- softmax over j (16 in-lane values + cross-quad shfl) ----
  float inv[4];
#pragma unroll
  for (int ni = 0; ni < 4; ++ni) {
    const int i = ni * 16 + col16;
    const int ix = i >> 3, iy = i & 7;
    float m = -3.4e38f;
#pragma unroll
    for (int mj = 0; mj < 4; ++mj)
#pragma unroll
      for (int r = 0; r < 4; ++r) {
        const int j = mj * 16 + q * 4 + r;
        float v = s[mj][ni][r] * 0.25f +
                  POS[((j >> 3) - ix + 7) * 15 + ((j & 7) - iy + 7)];
        if (lastRow && ((i ^ j) & 32)) v = -1e30f;
        if (lastCol && ((i ^ j) & 4))  v = -1e30f;
        s[mj][ni][r] = v;
        m = fmaxf(m, v);
      }
    m = fmaxf(m, __shfl_xor(m, 16, 64));
    m = fmaxf(m, __shfl_xor(m, 32, 64));
    float sum = 0.f;
#pragma unroll
    for (int mj = 0; mj < 4; ++mj)
#pragma unroll
      for (int r = 0; r < 4; ++r) {
        float e = __expf(s[mj][ni][r] - m);
        s[mj][ni][r] = e;
        sum += e;
      }
    sum += __shfl_xor(sum, 16, 64);
    sum += __shfl_xor(sum, 32, 64);
    inv[ni] = __builtin_amdgcn_rcpf(sum);
  }

  // ---- PV: O^T[e][i] (lane col = i-token, rows = e) ----
  f32x4 oacc[4] = {};
#pragma unroll
  for (int ks2 = 0; ks2 < 2; ++ks2) {
#pragma unroll
    for (int ni = 0; ni < 4; ++ni) {
      bf16x8 bP;
#pragma unroll
      for (int jj = 0; jj < 8; ++jj)
        bP[jj] = (bf16_t)(s[2 * ks2 + (jj >> 2)][ni][jj & 3] * inv[ni]);
      oacc[ni] = __builtin_amdgcn_mfma_f32_16x16x32_bf16(aV[ks2], bP, oacc[ni], 0, 0, 0);
    }
  }
  // Y[token][h*16+e] bf16x4 writes
#pragma unroll
  for (int ni = 0; ni < 4; ++ni) {
    bf16x4 pk;
#pragma unroll
    for (int r = 0; r < 4; ++r) pk[r] = (bf16_t)(oacc[ni][r]);
    *(bf16x4*)(Y + (ni * 16 + col16) * 136 + h * 16 + q * 4) = pk;
  }
  __syncthreads();

  // ---- Phase 3: out = Y @ Wo + bo; wave w owns o-tile w ----
#pragma unroll
  for (int mi = 0; mi < 4; ++mi)
#pragma unroll
    for (int ks = 0; ks < 4; ++ks)
      xf[mi][ks] = *(const bf16x8*)(Y + (mi * 16 + col16) * 136 + ks * 32 + q * 8);
  f32x4 acc[4] = {};
#pragma unroll
  for (int ks = 0; ks < 4; ++ks) {
    bf16x8 bWo = *(const bf16x8*)(wsW + 81920 + (w * 4 + ks) * 512 + l * 8);
#pragma unroll
    for (int mi = 0; mi < 4; ++mi)
      acc[mi] = __builtin_amdgcn_mfma_f32_16x16x32_bf16(xf[mi][ks], bWo, acc[mi], 0, 0, 0);
  }
  const int o = w * 16 + col16;
  const float bias = bo[o];
  const int rg0 = wy << 3, cg0 = wx << 3;
#pragma unroll
  for (int mi = 0; mi < 4; ++mi)
#pragma unroll
    for (int r = 0; r < 4; ++r) {
      const int t = mi * 16 + q * 4 + r;
      const int rg = rg0 + (t >> 3), cg = cg0 + (t & 7);
      out[(((size_t)b * 65536 + (size_t)rg * 256 + (size_t)cg) << 7) + o] =
          acc[mi][r] + bias;
    }
}

extern "C" void kernel_launch(void* const* d_in, const int* in_sizes, int n_in,
                              void* d_out, int out_size, void* d_ws, size_t ws_size,
                              hipStream_t stream) {
  const float* gxv = (const float*)d_in[0];
  const float* gxc = (const float*)d_in[1];
  const float* Wv  = (const float*)d_in[2];
  const float* bv  = (const float*)d_in[3];
  const float* Wc  = (const float*)d_in[4];
  const float* bc  = (const float*)d_in[5];
  const float* pe  = (const float*)d_in[6];
  const float* Wo  = (const float*)d_in[7];
  const float* bo  = (const float*)d_in[8];
  float* out = (float*)d_out;
  bf16_t* wsW = (bf16_t*)d_ws;   // 192KB fragment-ordered bf16 weights

  hipFuncSetAttribute((const void*)swin_fused_k,
                      hipFuncAttributeMaxDynamicSharedMemorySize, SMEM_BYTES);
  prep_weights_k<<<192, 512, 0, stream>>>(Wv, Wc, Wo, wsW);
  swin_fused_k<<<4096, 512, SMEM_BYTES, stream>>>(gxv, gxc, bv, bc, pe, bo, wsW, out);
}